// Round 6
// baseline (57766.309 us; speedup 1.0000x reference)
//
#include <hip/hip_runtime.h>

#define TT    8192
#define HD    1024
#define NBLK  64        // compute blocks; 16 hidden units per block
#define NPW   8         // producer waves per block, 2 units each
#define NTHR  ((NPW + 1) * 64)   // 576: waves 0..7 producers, wave 8 poller
#define NBUF  8         // ring depth (max inter-block skew is 1 step)

typedef int i32x4 __attribute__((ext_vector_type(4)));
typedef int i32x2 __attribute__((ext_vector_type(2)));

// ---- MALL-coherent accesses (sc0 sc1: bypass L1+L2, coherent chip-wide) ---
__device__ __forceinline__ void llc_store4(unsigned* p, unsigned a, unsigned b,
                                           unsigned c, unsigned d) {
  i32x4 v; v.x = (int)a; v.y = (int)b; v.z = (int)c; v.w = (int)d;
  asm volatile("global_store_dwordx4 %0, %1, off sc0 sc1"
               :: "v"(p), "v"(v) : "memory");
}

__device__ __forceinline__ float sigf(float z) {
  return 1.0f / (1.0f + __expf(-z));
}
__device__ __forceinline__ float tanh_fast(float z) {
  float az = fabsf(z);
  float e  = __expf(2.0f * az);          // >= 1
  float t  = 1.0f - 2.0f / (e + 1.0f);
  return z < 0.0f ? -t : t;
}

#define FMA4(acc, hvv, wvv)                                      \
  acc = fmaf((hvv).x, (wvv).x, acc);                             \
  acc = fmaf((hvv).y, (wvv).y, acc);                             \
  acc = fmaf((hvv).z, (wvv).z, acc);                             \
  acc = fmaf((hvv).w, (wvv).w, acc);

// hbuf: unsigned[NBUF][HD][2] fused {value, tag}; h_t -> slot t%8, tag t+1.
// Producer wave w of block b publishes units {b*16+2w, b*16+2w+1} as ONE
// aligned 16-B store {vA, t+1, vB, t+1} — if the fabric splits it, each 8-B
// half is still self-certifying (tag adjacent to its value).
//
// DETECT (single hop): wave 8 of EVERY block polls all 1024 pairs with 8
// coalesced dwordx4 per lane (lane l, load j covers units {j*128+2l, +1});
// the load that sees all tags==t already carries h_{t-1}.  Producer CUs
// issue NO loads — their store enters a quiet VMEM pipe (the r2/r5 lesson:
// publication must not queue behind sibling polls).
//
// RING SAFETY (NBUF=8): block A's poller detects step t only after every
// block stored h_{t-1}, which required every block's poller to detect step
// t-1 (vmcnt(0)-completed reads).  So inter-block skew <= 1 step; slot t%8
// is overwritten 8 steps after last possible read.  QED.
// PROJECTION: rotating block's poller holds all 1024 values in registers
// after detect; it computes out[t-1] AFTER the release barrier, overlapped
// with the producers' compute phase — off the critical path.
extern "C" __global__ __launch_bounds__(NTHR, 1)
void lstm_persistent(const float* __restrict__ x,
                     const float* __restrict__ W_ih,
                     const float* __restrict__ W_hh,
                     const float* __restrict__ b_ih,
                     const float* __restrict__ b_hh,
                     const float* __restrict__ W_fc,
                     const float* __restrict__ b_fc,
                     float* __restrict__ out,
                     unsigned* __restrict__ hbuf)
{
  const int tid  = threadIdx.x;
  const int blk  = blockIdx.x;
  const int wave = tid >> 6;
  const int lane = tid & 63;

  __shared__ float x_lds[TT];          // 32 KB: whole input sequence
  __shared__ float h_lds[2][HD];       //  8 KB: double-buffered h broadcast

  // ---- one-time staging -------------------------------------------------
  for (int i = tid; i < TT / 4; i += NTHR)
    ((float4*)x_lds)[i] = ((const float4*)x)[i];

  const int g  = lane >> 4;            // gate 0..3 (i,f,g,o)
  const int kc = lane & 15;            // k-chunk within the 1024-dot
  const int ubase = blk * 16 + 2 * wave;   // producer waves only

  float4 w4a[16], w4b[16];
  float  wihA[4], bsA[4], wihB[4], bsB[4];
  float2 wfc2[8];
  float  bfc_val = 0.0f;

  if (wave < NPW) {
    // W_hh rows (gate g) for units ubase, ubase+1 — lane covers
    // k = m*64 + kc*4 + {0..3}
    const float* wra = W_hh + (size_t)(g * HD + ubase) * HD + kc * 4;
    const float* wrb = wra + HD;
#pragma unroll
    for (int m = 0; m < 16; ++m) {
      w4a[m] = *((const float4*)(wra + m * 64));
      w4b[m] = *((const float4*)(wrb + m * 64));
    }
#pragma unroll
    for (int q = 0; q < 4; ++q) {
      int r = q * HD + ubase;
      wihA[q] = W_ih[r];     bsA[q] = b_ih[r] + b_hh[r];
      wihB[q] = W_ih[r + 1]; bsB[q] = b_ih[r + 1] + b_hh[r + 1];
    }
  } else {
    // poller wave doubles as projector: W_fc fragment for its pair layout
#pragma unroll
    for (int j = 0; j < 8; ++j)
      wfc2[j] = *((const float2*)(W_fc + j * 128 + 2 * lane));
    bfc_val = b_fc[0];
  }
  float cA = 0.0f, cB = 0.0f;
  __syncthreads();                     // x_lds ready

  // ---- the sequential scan ----------------------------------------------
  for (int t = 0; t < TT; ++t) {
    i32x4 P0, P1, P2, P3, P4, P5, P6, P7;   // poller: pairs of h_{t-1}

    if (wave == NPW && t > 0) {
      // ---- single-hop detect: self-verify all 1024 fused pairs ----------
      const int want = t;
      const unsigned* pp0 =
          hbuf + (size_t)((t - 1) & (NBUF - 1)) * HD * 2 + lane * 4;
      const unsigned* pp1 = pp0 + 1024;      // +4 KB
      for (;;) {
        asm volatile(
          "global_load_dwordx4 %0, %8, off sc0 sc1\n\t"
          "global_load_dwordx4 %1, %8, off offset:1024 sc0 sc1\n\t"
          "global_load_dwordx4 %2, %8, off offset:2048 sc0 sc1\n\t"
          "global_load_dwordx4 %3, %8, off offset:3072 sc0 sc1\n\t"
          "global_load_dwordx4 %4, %9, off sc0 sc1\n\t"
          "global_load_dwordx4 %5, %9, off offset:1024 sc0 sc1\n\t"
          "global_load_dwordx4 %6, %9, off offset:2048 sc0 sc1\n\t"
          "global_load_dwordx4 %7, %9, off offset:3072 sc0 sc1\n\t"
          "s_waitcnt vmcnt(0)"
          : "=&v"(P0), "=&v"(P1), "=&v"(P2), "=&v"(P3),
            "=&v"(P4), "=&v"(P5), "=&v"(P6), "=&v"(P7)
          : "v"(pp0), "v"(pp1)
          : "memory");
        bool ok = (P0.y == want) && (P0.w == want) &&
                  (P1.y == want) && (P1.w == want) &&
                  (P2.y == want) && (P2.w == want) &&
                  (P3.y == want) && (P3.w == want) &&
                  (P4.y == want) && (P4.w == want) &&
                  (P5.y == want) && (P5.w == want) &&
                  (P6.y == want) && (P6.w == want) &&
                  (P7.y == want) && (P7.w == want);
        if (__all(ok)) break;
      }
      // extract: h[j*128+2*lane (+1)] -- 8 x ds_write_b64, 2-way bank (free)
      float* hb = h_lds[t & 1];
#define HWR(j, Pj) *(float2*)(hb + (j) * 128 + 2 * lane) =                 \
          make_float2(__int_as_float((Pj).x), __int_as_float((Pj).z));
      HWR(0, P0) HWR(1, P1) HWR(2, P2) HWR(3, P3)
      HWR(4, P4) HWR(5, P5) HWR(6, P6) HWR(7, P7)
#undef HWR
    }
    __syncthreads();                   // h_{t-1} broadcast complete

    if (wave < NPW) {
      float accA = 0.0f, accB = 0.0f;
      if (t > 0) {
        const float* hp = h_lds[t & 1] + kc * 4;
        float s0a = 0.f, s1a = 0.f, s2a = 0.f, s3a = 0.f;
        float s0b = 0.f, s1b = 0.f, s2b = 0.f, s3b = 0.f;
#pragma unroll
        for (int mb = 0; mb < 4; ++mb) {
          float4 ha = *((const float4*)(hp + (mb * 4 + 0) * 64));
          float4 hc = *((const float4*)(hp + (mb * 4 + 1) * 64));
          float4 he = *((const float4*)(hp + (mb * 4 + 2) * 64));
          float4 hg = *((const float4*)(hp + (mb * 4 + 3) * 64));
          FMA4(s0a, ha, w4a[mb * 4 + 0]);  FMA4(s0b, ha, w4b[mb * 4 + 0]);
          FMA4(s1a, hc, w4a[mb * 4 + 1]);  FMA4(s1b, hc, w4b[mb * 4 + 1]);
          FMA4(s2a, he, w4a[mb * 4 + 2]);  FMA4(s2b, he, w4b[mb * 4 + 2]);
          FMA4(s3a, hg, w4a[mb * 4 + 3]);  FMA4(s3b, hg, w4b[mb * 4 + 3]);
        }
        accA = (s0a + s1a) + (s2a + s3a);
        accB = (s0b + s1b) + (s2b + s3b);
      }
      // 4-round butterfly over kc (both units), then gate broadcasts
#pragma unroll
      for (int s = 1; s < 16; s <<= 1) {
        accA += __shfl_xor(accA, s);
        accB += __shfl_xor(accB, s);
      }
      float giA = __shfl(accA, 0),  giB = __shfl(accB, 0);
      float gfA = __shfl(accA, 16), gfB = __shfl(accB, 16);
      float ggA = __shfl(accA, 32), ggB = __shfl(accB, 32);
      float goA = __shfl(accA, 48), goB = __shfl(accB, 48);

      float xt = x_lds[t];
      giA += fmaf(xt, wihA[0], bsA[0]);  giB += fmaf(xt, wihB[0], bsB[0]);
      gfA += fmaf(xt, wihA[1], bsA[1]);  gfB += fmaf(xt, wihB[1], bsB[1]);
      ggA += fmaf(xt, wihA[2], bsA[2]);  ggB += fmaf(xt, wihB[2], bsB[2]);
      goA += fmaf(xt, wihA[3], bsA[3]);  goB += fmaf(xt, wihB[3], bsB[3]);
      cA = sigf(gfA) * cA + sigf(giA) * tanh_fast(ggA);
      cB = sigf(gfB) * cB + sigf(giB) * tanh_fast(ggB);
      float hA = sigf(goA) * tanh_fast(cA);
      float hB = sigf(goB) * tanh_fast(cB);

      if (lane == 0) {
        // fused publication: {vA, tag, vB, tag} in one aligned 16-B store
        llc_store4(hbuf + ((size_t)(t & (NBUF - 1)) * HD + ubase) * 2,
                   __float_as_uint(hA), (unsigned)(t + 1),
                   __float_as_uint(hB), (unsigned)(t + 1));
      }
    } else if (t > 0 && blk == ((t - 1) & (NBLK - 1))) {
      // ---- projection for step t-1: values already in P0..P7 ------------
      float p = 0.f;
#define PRJ(j, Pj) p = fmaf(__int_as_float((Pj).x), wfc2[j].x, p);         \
                   p = fmaf(__int_as_float((Pj).z), wfc2[j].y, p);
      PRJ(0, P0) PRJ(1, P1) PRJ(2, P2) PRJ(3, P3)
      PRJ(4, P4) PRJ(5, P5) PRJ(6, P6) PRJ(7, P7)
#undef PRJ
#pragma unroll
      for (int s = 1; s < 64; s <<= 1) p += __shfl_xor(p, s);
      if (lane == 0) out[t - 1] = p + bfc_val;
    }
  }

  // ---- epilogue: out[TT-1] by the rotating block's poller ----------------
  if (wave == NPW && blk == ((TT - 1) & (NBLK - 1))) {
    const int want = TT;
    const unsigned* pp0 =
        hbuf + (size_t)((TT - 1) & (NBUF - 1)) * HD * 2 + lane * 4;
    const unsigned* pp1 = pp0 + 1024;
    i32x4 P0, P1, P2, P3, P4, P5, P6, P7;
    for (;;) {
      asm volatile(
        "global_load_dwordx4 %0, %8, off sc0 sc1\n\t"
        "global_load_dwordx4 %1, %8, off offset:1024 sc0 sc1\n\t"
        "global_load_dwordx4 %2, %8, off offset:2048 sc0 sc1\n\t"
        "global_load_dwordx4 %3, %8, off offset:3072 sc0 sc1\n\t"
        "global_load_dwordx4 %4, %9, off sc0 sc1\n\t"
        "global_load_dwordx4 %5, %9, off offset:1024 sc0 sc1\n\t"
        "global_load_dwordx4 %6, %9, off offset:2048 sc0 sc1\n\t"
        "global_load_dwordx4 %7, %9, off offset:3072 sc0 sc1\n\t"
        "s_waitcnt vmcnt(0)"
        : "=&v"(P0), "=&v"(P1), "=&v"(P2), "=&v"(P3),
          "=&v"(P4), "=&v"(P5), "=&v"(P6), "=&v"(P7)
        : "v"(pp0), "v"(pp1)
        : "memory");
      bool ok = (P0.y == want) && (P0.w == want) &&
                (P1.y == want) && (P1.w == want) &&
                (P2.y == want) && (P2.w == want) &&
                (P3.y == want) && (P3.w == want) &&
                (P4.y == want) && (P4.w == want) &&
                (P5.y == want) && (P5.w == want) &&
                (P6.y == want) && (P6.w == want) &&
                (P7.y == want) && (P7.w == want);
      if (__all(ok)) break;
    }
    float p = 0.f;
#define PRJ(j, Pj) p = fmaf(__int_as_float((Pj).x), wfc2[j].x, p);         \
                   p = fmaf(__int_as_float((Pj).z), wfc2[j].y, p);
    PRJ(0, P0) PRJ(1, P1) PRJ(2, P2) PRJ(3, P3)
    PRJ(4, P4) PRJ(5, P5) PRJ(6, P6) PRJ(7, P7)
#undef PRJ
#pragma unroll
    for (int s = 1; s < 64; s <<= 1) p += __shfl_xor(p, s);
    if (lane == 0) out[TT - 1] = p + bfc_val;
  }
}

extern "C" void kernel_launch(void* const* d_in, const int* in_sizes, int n_in,
                              void* d_out, int out_size, void* d_ws, size_t ws_size,
                              hipStream_t stream) {
  const float* x   = (const float*)d_in[0];
  const float* Wih = (const float*)d_in[1];
  const float* Whh = (const float*)d_in[2];
  const float* bih = (const float*)d_in[3];
  const float* bhh = (const float*)d_in[4];
  const float* Wfc = (const float*)d_in[5];
  const float* bfc = (const float*)d_in[6];
  float* out = (float*)d_out;

  unsigned* hbuf = (unsigned*)d_ws;
  // zero all tags (0 never equals any wanted tag >= 1)
  size_t init_bytes = (size_t)(NBUF * HD * 2) * sizeof(unsigned);
  hipMemsetAsync(d_ws, 0, init_bytes, stream);
  hipLaunchKernelGGL(lstm_persistent, dim3(NBLK), dim3(NTHR), 0, stream,
                     x, Wih, Whh, bih, bhh, Wfc, bfc, out, hbuf);
}

// Round 10
// 23227.480 us; speedup vs baseline: 2.4870x; 2.4870x over previous
//
#include <hip/hip_runtime.h>

#define TT    8192
#define HD    1024
#define NBLK  256       // compute blocks; block NBLK is the dedicated sequencer
#define NTHR  256
#define NBUF  4         // pair-ring depth — safety proof below
#define NREP  8         // flag replicas, one 64B line each

typedef int i32x4 __attribute__((ext_vector_type(4)));
typedef int i32x2 __attribute__((ext_vector_type(2)));

// ---- LLC-coherent accesses (sc0 sc1 = bypass L1+L2, coherent at MALL) ----
__device__ __forceinline__ void llc_load_pair(const unsigned* p, i32x4& a, i32x4& b) {
  asm volatile("global_load_dwordx4 %0, %2, off sc0 sc1\n\t"
               "global_load_dwordx4 %1, %3, off sc0 sc1\n\t"
               "s_waitcnt vmcnt(0)"
               : "=&v"(a), "=&v"(b)
               : "v"(p), "v"(p + 4)
               : "memory");
}
__device__ __forceinline__ unsigned llc_load1(const unsigned* p) {
  unsigned r;
  asm volatile("global_load_dword %0, %1, off sc0 sc1\n\ts_waitcnt vmcnt(0)"
               : "=v"(r) : "v"(p) : "memory");
  return r;
}
__device__ __forceinline__ void llc_store2(unsigned* p, unsigned lo, unsigned hi) {
  i32x2 v; v.x = (int)lo; v.y = (int)hi;
  asm volatile("global_store_dwordx2 %0, %1, off sc0 sc1"
               :: "v"(p), "v"(v) : "memory");
}
__device__ __forceinline__ void llc_store1(unsigned* p, unsigned v) {
  asm volatile("global_store_dword %0, %1, off sc0 sc1"
               :: "v"(p), "v"(v) : "memory");
}

__device__ __forceinline__ float sigf(float z) {
  return 1.0f / (1.0f + __expf(-z));
}
__device__ __forceinline__ float tanh_fast(float z) {
  float az = fabsf(z);
  float e  = __expf(2.0f * az);          // >= 1
  float t  = 1.0f - 2.0f / (e + 1.0f);
  return z < 0.0f ? -t : t;
}

#define FMA4(acc, hvv, wvv)                                      \
  acc = fmaf((hvv).x, (wvv).x, acc);                             \
  acc = fmaf((hvv).y, (wvv).y, acc);                             \
  acc = fmaf((hvv).z, (wvv).z, acc);                             \
  acc = fmaf((hvv).w, (wvv).w, acc);

// hbuf: unsigned[NBUF][HD][2] {value_bits, tag}; h of step t -> ring t%NBUF,
// tag t+1 (single 8-B store: tag certifies value).
// flag[r*16]: replicas; flag >= t  <=>  the SEQUENCER verified all 1024 tags
// of step t-1 at the MALL.  Consumers therefore read pairs WITHOUT verifying.
//
// RING SAFETY (NBUF=4): producer P overwrites slot (t-1)%4 at step t+3 only
// after its gate saw flag >= t+3.  The sequencer raises flag t+3 only after
// every block stored h_{t+2}; a block stores h_{t+2} only after reading
// h_{t+1}, which required flag >= t+2, which required every block to have
// stored h_{t+1}, which required reading h_t from slot (t-1)%4.  Hence all
// step-t reads of that slot are complete before any overwrite.  QED.
extern "C" __global__ __launch_bounds__(NTHR, 1)
void lstm_persistent(const float* __restrict__ x,
                     const float* __restrict__ W_ih,
                     const float* __restrict__ W_hh,
                     const float* __restrict__ b_ih,
                     const float* __restrict__ b_hh,
                     const float* __restrict__ W_fc,
                     const float* __restrict__ b_fc,
                     float* __restrict__ out,
                     unsigned* __restrict__ flag,
                     unsigned* __restrict__ hbuf)
{
  const int tid = threadIdx.x;
  const int blk = blockIdx.x;

  // ================= block NBLK: dedicated sequencer =====================
  // Polls tag words during the producers' store window; raises the flag one
  // detect-latency after the LAST store of each step (no compute in between).
  if (blk == NBLK) {
    for (int t = 0; t < TT; ++t) {
      const unsigned* src = hbuf + (((t & (NBUF - 1)) * HD + tid * 4) * 2);
      i32x4 A, B;
      const int want = t + 1;
      do {
        llc_load_pair(src, A, B);
      } while (!(A.y == want && A.w == want && B.y == want && B.w == want));
      __syncthreads();                    // all 1024 tags verified
      if (tid < NREP)
        llc_store1(flag + (tid << 4), (unsigned)want);
    }
    return;
  }

  // ================= blocks 0..255: compute ==============================
  __shared__ float x_lds[TT];     // 32 KB: whole input sequence
  __shared__ float h_lds[HD];     //  4 KB: broadcast of h_{t-1}

  const int wave = tid >> 6;
  const int lane = tid & 63;
  const int g    = lane >> 4;     // gate 0..3 (i,f,g,o)
  const int kc   = lane & 15;     // k-chunk within the 1024-dot
  const int unit = blk * 4 + wave;

  // ---- one-time staging -------------------------------------------------
  for (int i = tid; i < TT / 4; i += NTHR)
    ((float4*)x_lds)[i] = ((const float4*)x)[i];

  // W_hh row (gate g, unit) — lane covers k = m*64 + kc*4 + {0..3}
  float4 w4[16];
  {
    const float* wr = W_hh + (size_t)(g * HD + unit) * HD + kc * 4;
#pragma unroll
    for (int m = 0; m < 16; ++m)
      w4[m] = *((const float4*)(wr + m * 64));
  }
  float4 wfc4[4];
#pragma unroll
  for (int m = 0; m < 4; ++m)
    wfc4[m] = *((const float4*)(W_fc + m * 256 + lane * 4));
  const float bfc_val = b_fc[0];

  float wih_g[4], bs_g[4];
#pragma unroll
  for (int q = 0; q < 4; ++q) {
    int r = q * HD + unit;
    wih_g[q] = W_ih[r];
    bs_g[q]  = b_ih[r] + b_hh[r];
  }
  float c_state = 0.0f;
  __syncthreads();                // x_lds ready

  const unsigned* flag_mine = flag + ((blk & (NREP - 1)) << 4);

  // ---- the sequential scan ---------------------------------------------
  for (int t = 0; t < TT; ++t) {
    const bool doproj = (t > 0) && (wave == 1) && (blk == (t & 255));
    float accs = 0.0f;
    float4 hp4[4];

    if (t > 0) {
      // gate: replica flag (1 coalesced same-address tx per wave per round)
      while (llc_load1(flag_mine) < (unsigned)t) { }
      // certified single-shot read: flag guarantees tags==t, no verify loop
      const unsigned* src = hbuf + (((t - 1) & (NBUF - 1)) * HD + tid * 4) * 2;
      i32x4 A, B;
      llc_load_pair(src, A, B);
      float4 hv;
      hv.x = __int_as_float(A.x); hv.y = __int_as_float(A.z);
      hv.z = __int_as_float(B.x); hv.w = __int_as_float(B.z);
      ((float4*)h_lds)[tid] = hv;
      __syncthreads();

      // fragments + 64 FMAs (4 independent sub-chains)
      const float* hp = h_lds + kc * 4;
      float s0 = 0.f, s1 = 0.f, s2 = 0.f, s3 = 0.f;
#pragma unroll
      for (int mb = 0; mb < 4; ++mb) {
        float4 ha = *((const float4*)(hp + (mb * 4 + 0) * 64));
        float4 hb = *((const float4*)(hp + (mb * 4 + 1) * 64));
        float4 hc = *((const float4*)(hp + (mb * 4 + 2) * 64));
        float4 hd = *((const float4*)(hp + (mb * 4 + 3) * 64));
        FMA4(s0, ha, w4[mb * 4 + 0]);
        FMA4(s1, hb, w4[mb * 4 + 1]);
        FMA4(s2, hc, w4[mb * 4 + 2]);
        FMA4(s3, hd, w4[mb * 4 + 3]);
      }
      accs = (s0 + s1) + (s2 + s3);

      if (doproj) {
#pragma unroll
        for (int m = 0; m < 4; ++m)
          hp4[m] = *((const float4*)(h_lds + m * 256 + lane * 4));
      }
    }

    // 4-round butterfly over kc: each 16-lane gate-group gets its gate sum
#pragma unroll
    for (int s = 1; s < 16; s <<= 1)
      accs += __shfl_xor(accs, s);

    // SOLE DELTA vs the measured 23.17 ms baseline: per-gate PARALLEL
    // activation (each 16-lane group evaluates its own sigf/tanh) instead
    // of lane 0 serially evaluating 4 dependent __expf chains before the
    // critical publication store.  Same arithmetic, same operands.
    float xt = x_lds[t];
    float a  = accs + fmaf(xt, wih_g[g], bs_g[g]);
    float act = (g == 2) ? tanh_fast(a) : sigf(a);

    float si = __shfl(act, 0);
    float sf = __shfl(act, 16);
    float sg = __shfl(act, 32);
    float so = __shfl(act, 48);

    if (lane == 0) {
      c_state  = sf * c_state + si * sg;
      float hn = so * tanh_fast(c_state);
      llc_store2(hbuf + (((t & (NBUF - 1)) * HD + unit) * 2),
                 __float_as_uint(hn), (unsigned)(t + 1));  // fire & forget
    }

    // fused output projection for step t-1 (register-only, off crit path)
    if (doproj) {
      float p = 0.f;
#pragma unroll
      for (int m = 0; m < 4; ++m) { FMA4(p, hp4[m], wfc4[m]); }
#pragma unroll
      for (int s = 1; s < 64; s <<= 1) p += __shfl_xor(p, s);
      if (lane == 0) out[t - 1] = p + bfc_val;
    }
  }

  // ---- epilogue: out[TT-1] by block 0 (tag-verified direct read) ---------
  if (blk == 0) {
    const unsigned* src = hbuf + (((TT - 1) & (NBUF - 1)) * HD + tid * 4) * 2;
    i32x4 A, B;
    do {
      llc_load_pair(src, A, B);
    } while (!(A.y == TT && A.w == TT && B.y == TT && B.w == TT));
    float4 hv;
    hv.x = __int_as_float(A.x); hv.y = __int_as_float(A.z);
    hv.z = __int_as_float(B.x); hv.w = __int_as_float(B.z);
    ((float4*)h_lds)[tid] = hv;
    __syncthreads();
    if (wave == 1) {
      float p = 0.f;
#pragma unroll
      for (int m = 0; m < 4; ++m) {
        float4 hm = *((const float4*)(h_lds + m * 256 + lane * 4));
        FMA4(p, hm, wfc4[m]);
      }
#pragma unroll
      for (int s = 1; s < 64; s <<= 1) p += __shfl_xor(p, s);
      if (lane == 0) out[TT - 1] = p + bfc_val;
    }
  }
}

extern "C" void kernel_launch(void* const* d_in, const int* in_sizes, int n_in,
                              void* d_out, int out_size, void* d_ws, size_t ws_size,
                              hipStream_t stream) {
  const float* x   = (const float*)d_in[0];
  const float* Wih = (const float*)d_in[1];
  const float* Whh = (const float*)d_in[2];
  const float* bih = (const float*)d_in[3];
  const float* bhh = (const float*)d_in[4];
  const float* Wfc = (const float*)d_in[5];
  const float* bfc = (const float*)d_in[6];
  float* out = (float*)d_out;

  // ws layout: [flag: NREP lines of 64 B][hbuf: NBUF*HD tagged pairs = 32 KB]
  unsigned* flag = (unsigned*)d_ws;
  unsigned* hbuf = flag + NREP * 16;
  size_t init_bytes = (NREP * 16 + NBUF * HD * 2) * sizeof(unsigned);

  // zeros: tag 0 never equals any expected tag (>=1); flag 0 < any t
  hipMemsetAsync(d_ws, 0, init_bytes, stream);
  hipLaunchKernelGGL(lstm_persistent, dim3(NBLK + 1), dim3(NTHR), 0, stream,
                     x, Wih, Whh, bih, bhh, Wfc, bfc, out, flag, hbuf);
}